// Round 1
// baseline (78.199 us; speedup 1.0000x reference)
//
#include <hip/hip_runtime.h>
#include <math.h>

namespace {
constexpr int kB = 2, kC = 3, kOC = 2, kH = 96, kW = 96;
constexpr int kN      = kH * kW;        // 9216
constexpr int kChunks = kN / 256;       // 36
constexpr int kBlocks = kB * kChunks;   // 72  (<= 256 CUs -> all co-resident, grid barrier safe)
constexpr float kEps   = 1e-5f;
constexpr float kScale = 0.57735026918962576f;  // 1/sqrt(3)
// ws layout (floats):
constexpr int WS_P     = 0;     // 72 float4: per-block (sum0, sq0, sum1, sq1) -> floats [0,288)
constexpr int WS_CTR_B = 1280;  // byte offset of barrier counter (uint32), own cache line
}

// Single fused kernel:
//   phase A: block-redundant 3x3 Gram -> E -> conv taps (prefetched to regs) -> y in regs
//            + per-block stat partials to ws
//   device-wide barrier (atomic counter, 72 co-resident blocks, s_sleep spin)
//   phase B: wave-redundant shuffle reduce of 72 partials -> BN + LeakyReLU, y never left regs
__global__ __launch_bounds__(256) void k_fused(const float* __restrict__ X,
                                               const float* __restrict__ Xh,
                                               const float* __restrict__ cw,
                                               const float* __restrict__ cb,
                                               const float* __restrict__ gamma,
                                               const float* __restrict__ beta,
                                               float* __restrict__ ws,
                                               float* __restrict__ out) {
    const int tid = threadIdx.x;
    const int blk = blockIdx.x;              // 0..71
    const int b   = blk / kChunks;
    const int pix = (blk % kChunks) * 256 + tid;
    const int h = pix / kW, w = pix % kW;

    const float*  qb  = X  + (size_t)b * kC * kN;
    const float4* qb4 = (const float4*)qb;
    const float4* kb4 = (const float4*)(Xh + (size_t)b * kC * kN);

    // ---- Gram M[cp][c] = sum_n Xh[b,cp,n] * X[b,c,n]  (block-local, redundant)
    float m[9] = {0,0,0,0,0,0,0,0,0};
    #pragma unroll
    for (int it = 0; it < 9; ++it) {                     // covers kN/4 = 2304 float4
        const int n = it * 256 + tid;
        const float4 q0 = qb4[n], q1 = qb4[kN/4 + n], q2 = qb4[2*kN/4 + n];
        const float4 k0 = kb4[n], k1 = kb4[kN/4 + n], k2 = kb4[2*kN/4 + n];
        m[0] += k0.x*q0.x + k0.y*q0.y + k0.z*q0.z + k0.w*q0.w;
        m[1] += k0.x*q1.x + k0.y*q1.y + k0.z*q1.z + k0.w*q1.w;
        m[2] += k0.x*q2.x + k0.y*q2.y + k0.z*q2.z + k0.w*q2.w;
        m[3] += k1.x*q0.x + k1.y*q0.y + k1.z*q0.z + k1.w*q0.w;
        m[4] += k1.x*q1.x + k1.y*q1.y + k1.z*q1.z + k1.w*q1.w;
        m[5] += k1.x*q2.x + k1.y*q2.y + k1.z*q2.z + k1.w*q2.w;
        m[6] += k2.x*q0.x + k2.y*q0.y + k2.z*q0.z + k2.w*q0.w;
        m[7] += k2.x*q1.x + k2.y*q1.y + k2.z*q1.z + k2.w*q1.w;
        m[8] += k2.x*q2.x + k2.y*q2.y + k2.z*q2.z + k2.w*q2.w;
    }

    // ---- conv tap prefetch (branch-free predicated loads; issued BEFORE the
    //      shuffle reduce so L2 latency hides under it)
    float qt0[9], qt1[9], qt2[9];
    #pragma unroll
    for (int dh = 0; dh < 3; ++dh) {
        #pragma unroll
        for (int dw = 0; dw < 3; ++dw) {
            const int hh = h + dh - 1, ww = w + dw - 1;
            const bool ok = (hh >= 0) && (hh < kH) && (ww >= 0) && (ww < kW);
            const int p = ok ? hh * kW + ww : pix;       // always-valid address
            const int t = dh * 3 + dw;
            const float f0 = qb[p], f1 = qb[kN + p], f2 = qb[2 * kN + p];
            qt0[t] = ok ? f0 : 0.f;
            qt1[t] = ok ? f1 : 0.f;
            qt2[t] = ok ? f2 : 0.f;
        }
    }

    // ---- reduce Gram across wave + block
    #pragma unroll
    for (int off = 32; off > 0; off >>= 1) {
        #pragma unroll
        for (int j = 0; j < 9; ++j) m[j] += __shfl_down(m[j], off);
    }
    __shared__ float sMw[4][9];
    __shared__ float sM[9];
    __shared__ float sE[2][3][9];
    if ((tid & 63) == 0) {
        #pragma unroll
        for (int j = 0; j < 9; ++j) sMw[tid >> 6][j] = m[j];
    }
    __syncthreads();
    if (tid < 9) sM[tid] = sMw[0][tid] + sMw[1][tid] + sMw[2][tid] + sMw[3][tid];
    __syncthreads();
    // E[oc][cp][nb] = kScale * sum_ic W[oc,ic,nb] * M[cp,ic]
    if (tid < 54) {
        const int oc = tid / 27, r = tid % 27, cp = r / 9, nb = r % 9;
        sE[oc][cp][nb] = kScale * (cw[oc * 27 +      nb] * sM[cp * 3 + 0] +
                                   cw[oc * 27 +  9 + nb] * sM[cp * 3 + 1] +
                                   cw[oc * 27 + 18 + nb] * sM[cp * 3 + 2]);
    }
    __syncthreads();

    // ---- conv from register taps: y[oc,p] = cb[oc] + sum_nb sum_cp E[oc,cp,nb] * q[cp, p+nb]
    float acc0 = cb[0], acc1 = cb[1];
    #pragma unroll
    for (int t = 0; t < 9; ++t) {
        acc0 += qt0[t] * sE[0][0][t] + qt1[t] * sE[0][1][t] + qt2[t] * sE[0][2][t];
        acc1 += qt0[t] * sE[1][0][t] + qt1[t] * sE[1][1][t] + qt2[t] * sE[1][2][t];
    }

    // ---- per-block stat partials (sum, sumsq per oc)
    float v0 = acc0, v1 = acc0 * acc0, v2 = acc1, v3 = acc1 * acc1;
    #pragma unroll
    for (int off = 32; off > 0; off >>= 1) {
        v0 += __shfl_down(v0, off); v1 += __shfl_down(v1, off);
        v2 += __shfl_down(v2, off); v3 += __shfl_down(v3, off);
    }
    __shared__ float sP[4][4];
    if ((tid & 63) == 0) {
        const int wv = tid >> 6;
        sP[wv][0] = v0; sP[wv][1] = v1; sP[wv][2] = v2; sP[wv][3] = v3;
    }
    __syncthreads();
    if (tid < 4)
        ws[WS_P + blk * 4 + tid] = sP[0][tid] + sP[1][tid] + sP[2][tid] + sP[3][tid];

    // ---- device-wide barrier: writer-release / reader-acquire
    __syncthreads();                           // partial stores issued block-wide
    unsigned int* ctr = (unsigned int*)((char*)ws + WS_CTR_B);
    if (tid == 0) {
        __threadfence();                       // release: partials visible device-wide
        __hip_atomic_fetch_add(ctr, 1u, __ATOMIC_ACQ_REL, __HIP_MEMORY_SCOPE_AGENT);
        while (__hip_atomic_load(ctr, __ATOMIC_ACQUIRE, __HIP_MEMORY_SCOPE_AGENT) < (unsigned)kBlocks)
            __builtin_amdgcn_s_sleep(1);
    }
    __syncthreads();
    __threadfence();                           // acquire: invalidate stale L1/L2 lines

    // ---- wave-redundant reduce of the 72 partial float4s (no __syncthreads needed)
    const int lane = tid & 63;
    const float4* P4 = (const float4*)(ws + WS_P);
    float4 s = P4[lane];                       // lanes 0..63 cover partials 0..63
    if (lane < kBlocks - 64) {                 // lanes 0..7 also fold in 64..71
        const float4 e = P4[64 + lane];
        s.x += e.x; s.y += e.y; s.z += e.z; s.w += e.w;
    }
    #pragma unroll
    for (int off = 32; off > 0; off >>= 1) {
        s.x += __shfl_xor(s.x, off);
        s.y += __shfl_xor(s.y, off);
        s.z += __shfl_xor(s.z, off);
        s.w += __shfl_xor(s.w, off);
    }
    // every lane now holds the full (sum0, sq0, sum1, sq1)
    const float inv   = 1.f / (float)(kB * kN);
    const float mean0 = s.x * inv, mean1 = s.z * inv;
    const float g0 = gamma[0] * rsqrtf(s.y * inv - mean0 * mean0 + kEps);
    const float g1 = gamma[1] * rsqrtf(s.w * inv - mean1 * mean1 + kEps);
    const float y0 = (acc0 - mean0) * g0 + beta[0];
    const float y1 = (acc1 - mean1) * g1 + beta[1];
    out[(size_t)(b * kOC + 0) * kN + pix] = (y0 >= 0.f) ? y0 : 0.1f * y0;
    out[(size_t)(b * kOC + 1) * kN + pix] = (y1 >= 0.f) ? y1 : 0.1f * y1;
}

extern "C" void kernel_launch(void* const* d_in, const int* in_sizes, int n_in,
                              void* d_out, int out_size, void* d_ws, size_t ws_size,
                              hipStream_t stream) {
    const float* X      = (const float*)d_in[0];  // X_tnext     (2,3,96,96)
    const float* Xhat   = (const float*)d_in[1];  // X_hat_tnext (2,3,96,96)
    const float* conv_w = (const float*)d_in[2];  // (2,3,3,3)
    const float* conv_b = (const float*)d_in[3];  // (2,)
    const float* gamma  = (const float*)d_in[4];  // (2,)
    const float* beta   = (const float*)d_in[5];  // (2,)
    float* ws = (float*)d_ws;

    // ws is re-poisoned by the harness every iteration -> re-zero the barrier
    // counter in-stream (captured as a 4-byte memset node each graph replay).
    hipMemsetAsync((char*)d_ws + WS_CTR_B, 0, 4, stream);
    k_fused<<<kBlocks, 256, 0, stream>>>(X, Xhat, conv_w, conv_b, gamma, beta,
                                         ws, (float*)d_out);
}

// Round 4
// 71.351 us; speedup vs baseline: 1.0960x; 1.0960x over previous
//
#include <hip/hip_runtime.h>
#include <math.h>

// R3 resubmission of the R2 kernel (two infra failures, kernel never ran).

namespace {
constexpr int kB = 2, kC = 3, kOC = 2, kH = 96, kW = 96;
constexpr int kN      = kH * kW;        // 9216
constexpr int kChunks = kN / 256;       // 36
constexpr int kBlocks = kB * kChunks;   // 72
constexpr float kEps   = 1e-5f;
constexpr float kScale = 0.57735026918962576f;  // 1/sqrt(3)
// ws float layout:
constexpr int WS_P = 0;     // 72 float4: per-block (sum0, sq0, sum1, sq1)
constexpr int WS_Y = 512;   // 2*9216 float2: pre-BN y interleaved [b][pix][oc]
}

// kA: per-block Gram (redundant) -> algebraic conv fold (no E tensor, registers only)
//     -> y + stat partials.  Only 2 __syncthreads on the critical path.
__global__ __launch_bounds__(256) void kA_conv(const float* __restrict__ X,
                                               const float* __restrict__ Xh,
                                               const float* __restrict__ cw,
                                               const float* __restrict__ cb,
                                               float* __restrict__ ws) {
    const int tid = threadIdx.x;
    const int blk = blockIdx.x;              // 0..71
    const int b   = blk / kChunks;
    const int pix = (blk % kChunks) * 256 + tid;
    const int h = pix / kW, w = pix % kW;

    const float*  qb  = X  + (size_t)b * kC * kN;
    const float4* qb4 = (const float4*)qb;
    const float4* kb4 = (const float4*)(Xh + (size_t)b * kC * kN);

    // ---- Gram m[cp*3+c] = sum_n Xh[b,cp,n] * X[b,c,n]  (block-local, redundant)
    float m[9] = {0,0,0,0,0,0,0,0,0};
    #pragma unroll
    for (int it = 0; it < 9; ++it) {                     // covers kN/4 = 2304 float4
        const int n = it * 256 + tid;
        const float4 q0 = qb4[n], q1 = qb4[kN/4 + n], q2 = qb4[2*kN/4 + n];
        const float4 k0 = kb4[n], k1 = kb4[kN/4 + n], k2 = kb4[2*kN/4 + n];
        m[0] += k0.x*q0.x + k0.y*q0.y + k0.z*q0.z + k0.w*q0.w;
        m[1] += k0.x*q1.x + k0.y*q1.y + k0.z*q1.z + k0.w*q1.w;
        m[2] += k0.x*q2.x + k0.y*q2.y + k0.z*q2.z + k0.w*q2.w;
        m[3] += k1.x*q0.x + k1.y*q0.y + k1.z*q0.z + k1.w*q0.w;
        m[4] += k1.x*q1.x + k1.y*q1.y + k1.z*q1.z + k1.w*q1.w;
        m[5] += k1.x*q2.x + k1.y*q2.y + k1.z*q2.z + k1.w*q2.w;
        m[6] += k2.x*q0.x + k2.y*q0.y + k2.z*q0.z + k2.w*q0.w;
        m[7] += k2.x*q1.x + k2.y*q1.y + k2.z*q1.z + k2.w*q1.w;
        m[8] += k2.x*q2.x + k2.y*q2.y + k2.z*q2.z + k2.w*q2.w;
    }

    // ---- conv tap prefetch, branch-free, issued BEFORE the shuffle reduce so
    //      L2 latency hides under the 6-deep DS-permute chain
    float qt0[9], qt1[9], qt2[9];
    #pragma unroll
    for (int dh = 0; dh < 3; ++dh) {
        #pragma unroll
        for (int dw = 0; dw < 3; ++dw) {
            const int hh = h + dh - 1, ww = w + dw - 1;
            const bool ok = (hh >= 0) && (hh < kH) && (ww >= 0) && (ww < kW);
            const int p = ok ? hh * kW + ww : pix;       // always-valid address
            const int t = dh * 3 + dw;
            const float f0 = qb[p], f1 = qb[kN + p], f2 = qb[2 * kN + p];
            qt0[t] = ok ? f0 : 0.f;
            qt1[t] = ok ? f1 : 0.f;
            qt2[t] = ok ? f2 : 0.f;
        }
    }

    // ---- reduce Gram: wave butterfly, then one LDS hop, then per-thread total
    #pragma unroll
    for (int off = 32; off > 0; off >>= 1) {
        #pragma unroll
        for (int j = 0; j < 9; ++j) m[j] += __shfl_down(m[j], off);
    }
    __shared__ float sMw[4][9];
    if ((tid & 63) == 0) {
        #pragma unroll
        for (int j = 0; j < 9; ++j) sMw[tid >> 6][j] = m[j];
    }
    __syncthreads();                          // (barrier 1 of 2)
    float M[9];                               // wave-uniform, broadcast LDS reads
    #pragma unroll
    for (int j = 0; j < 9; ++j)
        M[j] = sMw[0][j] + sMw[1][j] + sMw[2][j] + sMw[3][j];

    // ---- algebraic conv fold (no E tensor, no LDS):
    //   S[ic][t]  = sum_cp qt_cp[t] * M[cp*3+ic]
    //   acc_oc    = cb[oc] + kScale * sum_ic sum_t cw[oc*27+ic*9+t] * S[ic][t]
    float S[3][9];
    #pragma unroll
    for (int t = 0; t < 9; ++t) {
        #pragma unroll
        for (int ic = 0; ic < 3; ++ic)
            S[ic][t] = qt0[t] * M[ic] + qt1[t] * M[3 + ic] + qt2[t] * M[6 + ic];
    }
    float t0 = 0.f, t1 = 0.f;
    #pragma unroll
    for (int ic = 0; ic < 3; ++ic) {
        #pragma unroll
        for (int t = 0; t < 9; ++t) {
            t0 += cw[     ic * 9 + t] * S[ic][t];   // uniform cw -> scalar loads
            t1 += cw[27 + ic * 9 + t] * S[ic][t];
        }
    }
    const float acc0 = cb[0] + kScale * t0;
    const float acc1 = cb[1] + kScale * t1;
    ((float2*)(ws + WS_Y))[(size_t)b * kN + pix] = make_float2(acc0, acc1);

    // ---- per-block stat partials (sum, sumsq per oc)
    float v0 = acc0, v1 = acc0 * acc0, v2 = acc1, v3 = acc1 * acc1;
    #pragma unroll
    for (int off = 32; off > 0; off >>= 1) {
        v0 += __shfl_down(v0, off); v1 += __shfl_down(v1, off);
        v2 += __shfl_down(v2, off); v3 += __shfl_down(v3, off);
    }
    __shared__ float sP[4][4];
    if ((tid & 63) == 0) {
        const int wv = tid >> 6;
        sP[wv][0] = v0; sP[wv][1] = v1; sP[wv][2] = v2; sP[wv][3] = v3;
    }
    __syncthreads();                          // (barrier 2 of 2)
    if (tid < 4)
        ws[WS_P + blk * 4 + tid] = sP[0][tid] + sP[1][tid] + sP[2][tid] + sP[3][tid];
}

// kB: wave-redundant butterfly reduce of the 72 partial float4s (0 barriers,
//     0 LDS), then BN (biased var) + gamma/beta + LeakyReLU.
__global__ __launch_bounds__(256) void kB_bn(const float* __restrict__ ws,
                                             const float* __restrict__ gamma,
                                             const float* __restrict__ beta,
                                             float* __restrict__ out) {
    const int tid = threadIdx.x;
    const int blk = blockIdx.x;              // 0..71
    const int b   = blk / kChunks;
    const int pix = (blk % kChunks) * 256 + tid;
    const int lane = tid & 63;

    // issue the y reload early; its latency hides under the reduce
    const float2 y2 = ((const float2*)(ws + WS_Y))[(size_t)b * kN + pix];

    const float4* P4 = (const float4*)(ws + WS_P);
    float4 s = P4[lane];                      // lanes 0..63 cover partials 0..63
    if (lane < kBlocks - 64) {                // lanes 0..7 fold in 64..71
        const float4 e = P4[64 + lane];
        s.x += e.x; s.y += e.y; s.z += e.z; s.w += e.w;
    }
    #pragma unroll
    for (int off = 32; off > 0; off >>= 1) {
        s.x += __shfl_xor(s.x, off);
        s.y += __shfl_xor(s.y, off);
        s.z += __shfl_xor(s.z, off);
        s.w += __shfl_xor(s.w, off);
    }
    // every lane holds the full (sum0, sq0, sum1, sq1)
    const float inv   = 1.f / (float)(kB * kN);
    const float mean0 = s.x * inv, mean1 = s.z * inv;
    const float g0 = gamma[0] * rsqrtf(s.y * inv - mean0 * mean0 + kEps);
    const float g1 = gamma[1] * rsqrtf(s.w * inv - mean1 * mean1 + kEps);
    const float y0 = (y2.x - mean0) * g0 + beta[0];
    const float y1 = (y2.y - mean1) * g1 + beta[1];
    out[(size_t)(b * kOC + 0) * kN + pix] = (y0 >= 0.f) ? y0 : 0.1f * y0;
    out[(size_t)(b * kOC + 1) * kN + pix] = (y1 >= 0.f) ? y1 : 0.1f * y1;
}

extern "C" void kernel_launch(void* const* d_in, const int* in_sizes, int n_in,
                              void* d_out, int out_size, void* d_ws, size_t ws_size,
                              hipStream_t stream) {
    const float* X      = (const float*)d_in[0];  // X_tnext     (2,3,96,96)
    const float* Xhat   = (const float*)d_in[1];  // X_hat_tnext (2,3,96,96)
    const float* conv_w = (const float*)d_in[2];  // (2,3,3,3)
    const float* conv_b = (const float*)d_in[3];  // (2,)
    const float* gamma  = (const float*)d_in[4];  // (2,)
    const float* beta   = (const float*)d_in[5];  // (2,)
    float* ws = (float*)d_ws;

    kA_conv<<<kBlocks, 256, 0, stream>>>(X, Xhat, conv_w, conv_b, ws);
    kB_bn  <<<kBlocks, 256, 0, stream>>>(ws, gamma, beta, (float*)d_out);
}